// Round 17
// baseline (385.736 us; speedup 1.0000x reference)
//
#include <hip/hip_runtime.h>
#include <math.h>

#define BB     4096
#define NN     32
#define EE     64
#define INDIM  74
#define HH     256
#define GCR    5
#define M1     1024
#define M2     512
#define FDIM   258
#define ADDD   2
#define FSTR   288     // Fh row stride (fp16), cols 258..287 zero
#define TSTR   36      // T column stride (halfwords): 72B -> 16 start banks
#define TGR    9216    // per-graph Tb region (8 waves * 32 cols * 36)

typedef __attribute__((ext_vector_type(8))) _Float16 half8_t;
typedef __attribute__((ext_vector_type(4))) float float4_t;
typedef __attribute__((ext_vector_type(16))) float float16_t;

#define MF16(a, b, c) __builtin_amdgcn_mfma_f32_16x16x32_f16((a), (b), (c), 0, 0, 0)
#define MF32(a, b, c) __builtin_amdgcn_mfma_f32_32x32x16_f16((a), (b), (c), 0, 0, 0)

// ---- ws layout (bytes) ----
#define WS_FH     0               // Fh fp16 [4096][288]
#define WS_WQK    4227072         // Wqk fp32 [256][256]
#define WS_TVEC   4489216         // tvec fp32 [256]
#define WS_PK     4490240         // packed fp16 fragments
// offsets in _Float16 units from PK base:
#define PK_WIN_HI 0
#define PK_G_BASE 49152
#define PK_G_STRIDE 131072
#define PK_WQK_HI 1359872
#define PK_W1P    1490944
#define PK_W2P    1785856

union H4 { unsigned long long u; _Float16 h[4]; };

__device__ __forceinline__ float16_t zero16() {
  float16_t z;
  #pragma unroll
  for (int e = 0; e < 16; ++e) z[e] = 0.f;
  return z;
}

// ---------------------------------------------------------------------------
// Prep 1: Wqk = Wq @ Wk^T (fp32), tvec = Wk @ bq
// ---------------------------------------------------------------------------
__global__ void prep1_kernel(const float* __restrict__ Wq, const float* __restrict__ Wk,
                             const float* __restrict__ bq,
                             float* __restrict__ wqkf, float* __restrict__ tvec) {
  const int i = blockIdx.x, j = threadIdx.x;
  if (i < 256) {
    __shared__ float qrow[256];
    qrow[j] = Wq[i * 256 + j];
    __syncthreads();
    float s = 0.f;
    for (int c = 0; c < 256; ++c) s = fmaf(qrow[c], Wk[j * 256 + c], s);
    wqkf[i * 256 + j] = s;
  } else {
    float s = 0.f;
    for (int c = 0; c < 256; ++c) s = fmaf(Wk[j * 256 + c], bq[c], s);
    tvec[j] = s;
  }
}

// ---------------------------------------------------------------------------
// Prep 2: pack weights into 32x32x16 MFMA fragment order, fp16.
// chunk: local = (nt*KS16 + ks)*64 + lane; elem i:
//   k = ks*16 + (lane>>5)*8 + i ; j = nt*32 + (lane&31) ; src = S[k*256+j]
// ---------------------------------------------------------------------------
template<int KS16, int KREAL>
__device__ __forceinline__ void pack32(const float* __restrict__ S,
                                       _Float16* __restrict__ dst, int local) {
  const int l = local & 63;
  const int nk = local >> 6;
  const int ks = nk % KS16;
  const int nt = nk / KS16;
  const int j = nt * 32 + (l & 31);
  const int kbase = ks * 16 + (l >> 5) * 8;
  half8_t h8;
  #pragma unroll
  for (int i = 0; i < 8; ++i) {
    const int k = kbase + i;
    h8[i] = (_Float16)((k < KREAL) ? S[k * 256 + j] : 0.f);
  }
  *(half8_t*)(dst + (size_t)local * 8) = h8;
}

__global__ void prep2_kernel(const float* __restrict__ W_in,
                             const float* __restrict__ W_g1, const float* __restrict__ W_g2,
                             const float* __restrict__ wqkf, _Float16* __restrict__ pk) {
  const int cid = blockIdx.x * 256 + threadIdx.x;
  if (cid < 3072) {                                 // 8nt * 6ks * 64
    pack32<6, 74>(W_in, pk + PK_WIN_HI, cid);
  } else {
    const int m = (cid - 3072) >> 13;               // 0..10, 8192 chunks each
    const int local = (cid - 3072) & 8191;
    if (m < 10) {
      const float* S = (m < 5) ? (W_g1 + (size_t)m * 65536) : (W_g2 + (size_t)(m - 5) * 65536);
      pack32<16, 256>(S, pk + PK_G_BASE + (size_t)m * PK_G_STRIDE, local);
    } else {
      pack32<16, 256>(wqkf, pk + PK_WQK_HI, local);
    }
  }
}

// ---------------------------------------------------------------------------
// Prep 3: pack MLP weights (W1 [258][1024], W2 [1024][512]) fp16 16x16-frag.
// ---------------------------------------------------------------------------
template<int KS, int KREAL, int NCOL>
__device__ __forceinline__ void pack_flat(const float* __restrict__ S,
                                          _Float16* __restrict__ dst, int local) {
  const int l = local & 63;
  const int nk = local >> 6;
  const int ks = nk % KS;
  const int nt = nk / KS;
  const int j = nt * 16 + (l & 15);
  const int kbase = ks * 32 + (l >> 4) * 8;
  half8_t h8;
  #pragma unroll
  for (int i = 0; i < 8; ++i) {
    const int k = kbase + i;
    h8[i] = (_Float16)((k < KREAL) ? S[(size_t)k * NCOL + j] : 0.f);
  }
  *(half8_t*)(dst + (size_t)local * 8) = h8;
}

__global__ void prep3_kernel(const float* __restrict__ W1, const float* __restrict__ W2,
                             _Float16* __restrict__ pk) {
  const int cid = blockIdx.x * 256 + threadIdx.x;
  if (cid < 36864) {
    pack_flat<9, 258, 1024>(W1, pk + PK_W1P, cid);
  } else {
    pack_flat<32, 1024, 512>(W2, pk + PK_W2P, cid - 36864);
  }
}

// ---------------------------------------------------------------------------
// conv via 32x32x16 MFMA. r17 fix: T column stride padded 32 -> 36 halfwords
// (72B). r16's 64B stride put every lane's T access in the SAME 2 banks
// (16-way, 6e7 conflicts); 72B walks all 16 even bank residues -> 2-way=free.
//   MFMA1: T = h @ W (acc 2x float16); T col-major, col j at j*TSTR.
//   barrier; MFMA2 (swapped): h'^T = T^T @ Nmat^T, B=nm regs, b64 row writes.
// Hs layout: n*256 + (j ^ ((n&15)<<3)).
// ---------------------------------------------------------------------------
template<int KS16, bool RELU>
__device__ __forceinline__ void conv32(
    _Float16* Hs, _Float16* Tb, const half8_t nm[2][2],
    const _Float16* __restrict__ Whi, const float* __restrict__ bias,
    int lane, int wv)
{
  const int r31 = lane & 31, g2 = lane >> 5;
  const int swA = (r31 & 15) << 3;
  _Float16* Tw0 = Tb + wv * (32 * TSTR);
  _Float16* Tw1 = Tb + TGR + wv * (32 * TSTR);

  float16_t acc0 = zero16(), acc1 = zero16();
  #pragma unroll 4
  for (int ks = 0; ks < KS16; ++ks) {
    const half8_t wh = *(const half8_t*)(Whi + ((size_t)(wv * KS16 + ks) * 64 + lane) * 8);
    const int k0 = ks * 16 + g2 * 8;
    const half8_t ha0 = *(const half8_t*)(Hs + (r31 * 256 + (k0 ^ swA)));
    const half8_t ha1 = *(const half8_t*)(Hs + 8192 + (r31 * 256 + (k0 ^ swA)));
    acc0 = MF32(ha0, wh, acc0);
    acc1 = MF32(ha1, wh, acc1);
  }
  // T store: C col = jl = r31; reg-quad q -> rows n0..n0+3, n0 = 8q+4g2
  const int swT = (r31 & 3) << 3;
  #pragma unroll
  for (int q = 0; q < 4; ++q) {
    const int n0 = 8 * q + 4 * g2;
    H4 p0, p1;
    #pragma unroll
    for (int jj = 0; jj < 4; ++jj) {
      p0.h[jj] = (_Float16)acc0[4 * q + jj];
      p1.h[jj] = (_Float16)acc1[4 * q + jj];
    }
    *(unsigned long long*)(Tw0 + r31 * TSTR + (n0 ^ swT)) = p0.u;
    *(unsigned long long*)(Tw1 + r31 * TSTR + (n0 ^ swT)) = p1.u;
  }

  __syncthreads();   // ALL waves' H reads complete

  // MFMA2: A[row=jl=r31][k=n'] = T[n'][jl] ; B = nm (Nmat^T frags)
  float16_t d0 = zero16(), d1 = zero16();
  #pragma unroll
  for (int ks2 = 0; ks2 < 2; ++ks2) {
    const int n0 = ks2 * 16 + g2 * 8;
    const half8_t t0 = *(const half8_t*)(Tw0 + r31 * TSTR + (n0 ^ swT));
    const half8_t t1 = *(const half8_t*)(Tw1 + r31 * TSTR + (n0 ^ swT));
    d0 = MF32(t0, nm[0][ks2], d0);
    d1 = MF32(t1, nm[1][ks2], d1);
  }
  // h'^T C: col = node n = r31; rows j = wv*32 + 8q + 4g2 + jj
  const int swn = (r31 & 15) << 3;
  #pragma unroll
  for (int q = 0; q < 4; ++q) {
    const int j0 = wv * 32 + 8 * q + 4 * g2;
    const float4 bb = *(const float4*)&bias[j0];
    H4 p0, p1;
    #pragma unroll
    for (int jj = 0; jj < 4; ++jj) {
      float v0 = d0[4 * q + jj] + ((const float*)&bb)[jj];
      float v1 = d1[4 * q + jj] + ((const float*)&bb)[jj];
      if (RELU) { v0 = fmaxf(v0, 0.f); v1 = fmaxf(v1, 0.f); }
      p0.h[jj] = (_Float16)v0;
      p1.h[jj] = (_Float16)v1;
    }
    *(unsigned long long*)(Hs + (r31 * 256 + (j0 ^ swn))) = p0.u;
    *(unsigned long long*)(Hs + 8192 + (r31 * 256 + (j0 ^ swn))) = p1.u;
  }
  __syncthreads();   // new h visible
}

// ---------------------------------------------------------------------------
// GNN kernel: 2 graphs/block, 512 threads. LDS: Hs 32K + Tb 36K + Sb 9.25K
// = 77.25 KB -> 2 blocks/CU under (512,4).
// ---------------------------------------------------------------------------
__global__ __launch_bounds__(512, 4)
void gnn_kernel(const float* __restrict__ x, const float* __restrict__ addf,
                const int* __restrict__ src, const int* __restrict__ dst,
                const float* __restrict__ b_in,
                const float* __restrict__ b_g1, const float* __restrict__ b_g2,
                const float* __restrict__ Wvp, const float* __restrict__ bv,
                const _Float16* __restrict__ pk,
                const float* __restrict__ tvec,
                _Float16* __restrict__ Fh)
{
  __shared__ __align__(16) _Float16 Hs[2][8192];
  __shared__ __align__(16) _Float16 Tb[2][TGR];
  __shared__ float Sb[2][1184];

  const int tid = threadIdx.x;
  const int lane = tid & 63;
  const int wv = tid >> 6;            // 0..7
  const int r31 = lane & 31, g2 = lane >> 5;
  const int g4 = lane >> 4, l15 = lane & 15;
  const int swA = (r31 & 15) << 3;
  const int ga = blockIdx.x * 2;

  // ---- build Nmat = diag(inorm) . A_adj . diag(onorm) for both graphs ----
  for (int i = tid; i < 2048; i += 512) Sb[i >> 10][i & 1023] = 0.f;
  __syncthreads();
  if (tid < 128) {
    const int gi = tid >> 6, e = tid & 63;
    const int es = src[(size_t)(ga + gi) * EE + e];
    const int ed = dst[(size_t)(ga + gi) * EE + e];
    atomicAdd(&Sb[gi][ed * 32 + es], 1.0f);
  }
  __syncthreads();
  if (tid < 64) {                       // inorm = rsqrt(row sums)
    const int gi = tid >> 5, n = tid & 31;
    float s = 0.f;
    for (int m = 0; m < NN; ++m) s += Sb[gi][n * 32 + m];
    Sb[gi][1056 + n] = 1.f / sqrtf(fmaxf(s, 1.f));
  } else if (tid < 128) {               // onorm = rsqrt(col sums)
    const int gi = (tid - 64) >> 5, n = tid & 31;
    float s = 0.f;
    for (int m = 0; m < NN; ++m) s += Sb[gi][m * 32 + n];
    Sb[gi][1088 + n] = 1.f / sqrtf(fmaxf(s, 1.f));
  }
  __syncthreads();
  for (int i = tid; i < 2048; i += 512) {
    const int gi = i >> 10, idx = i & 1023;
    Sb[gi][idx] *= Sb[gi][1056 + (idx >> 5)] * Sb[gi][1088 + (idx & 31)];
  }
  __syncthreads();

  // ---- Nmat^T B-frags into registers: nm[gi][ks2][i] = Nmat[n=l&31][n'] ----
  half8_t nm[2][2];
  #pragma unroll
  for (int gi = 0; gi < 2; ++gi)
    #pragma unroll
    for (int ks2 = 0; ks2 < 2; ++ks2)
      #pragma unroll
      for (int i = 0; i < 8; ++i)
        nm[gi][ks2][i] = (_Float16)Sb[gi][r31 * 32 + ks2 * 16 + g2 * 8 + i];

  // ---- stage x (fp16, cols 74..95 zero) ----
  for (int i = tid; i < 2 * NN * 96; i += 512) {
    const int gi = i / 3072, rem = i - gi * 3072;
    const int r = rem / 96, c = rem - r * 96;
    const float vx = (c < INDIM) ? x[(size_t)(ga + gi) * (NN * INDIM) + r * INDIM + c] : 0.f;
    Hs[gi][r * 256 + (c ^ ((r & 15) << 3))] = (_Float16)vx;
  }
  __syncthreads();

  // ---- 11 graph convolutions ----
  conv32<6, false>(&Hs[0][0], &Tb[0][0], nm, pk + PK_WIN_HI, b_in, lane, wv);
  #pragma unroll 1
  for (int L = 0; L < GCR; ++L) {
    conv32<16, true>(&Hs[0][0], &Tb[0][0], nm,
                     pk + PK_G_BASE + (size_t)L * PK_G_STRIDE, b_g1 + L * HH, lane, wv);
    conv32<16, true>(&Hs[0][0], &Tb[0][0], nm,
                     pk + PK_G_BASE + (size_t)(5 + L) * PK_G_STRIDE, b_g2 + L * HH, lane, wv);
  }

  // ---- attention: u'^T = Wqk^T @ h^T (32x32, swapped) -> row-major u' ----
  {
    const _Float16* Qp = pk + PK_WQK_HI;
    float16_t ua0 = zero16(), ua1 = zero16();
    #pragma unroll 4
    for (int ks = 0; ks < 16; ++ks) {
      const half8_t qf = *(const half8_t*)(Qp + ((size_t)(wv * 16 + ks) * 64 + lane) * 8);
      const int k0 = ks * 16 + g2 * 8;
      const half8_t hb0 = *(const half8_t*)(&Hs[0][r31 * 256 + (k0 ^ swA)]);
      const half8_t hb1 = *(const half8_t*)(&Hs[1][r31 * 256 + (k0 ^ swA)]);
      ua0 = MF32(qf, hb0, ua0);
      ua1 = MF32(qf, hb1, ua1);
    }
    const int swn = (r31 & 15) << 3;
    #pragma unroll
    for (int q = 0; q < 4; ++q) {
      const int j0 = wv * 32 + 8 * q + 4 * g2;
      const float4 tv = *(const float4*)&tvec[j0];
      H4 p0, p1;
      #pragma unroll
      for (int jj = 0; jj < 4; ++jj) {
        p0.h[jj] = (_Float16)(ua0[4 * q + jj] + ((const float*)&tv)[jj]);
        p1.h[jj] = (_Float16)(ua1[4 * q + jj] + ((const float*)&tv)[jj]);
      }
      *(unsigned long long*)(&Tb[0][r31 * 256 + (j0 ^ swn)]) = p0.u;
      *(unsigned long long*)(&Tb[1][r31 * 256 + (j0 ^ swn)]) = p1.u;
    }
  }
  __syncthreads();

  // ---- S = u' @ h^T (16x16, single 256-wide sweep; wave -> (sgi,smt,snt)) ----
  {
    const int sgi = wv >> 2, smt = (wv >> 1) & 1, snt = wv & 1;
    const int sw = l15 << 3;
    float4_t sacc = (float4_t){0.f, 0.f, 0.f, 0.f};
    #pragma unroll
    for (int ksl = 0; ksl < 8; ++ksl) {
      const int kl = ksl * 32 + g4 * 8;
      const half8_t ua = *(const half8_t*)(&Tb[sgi][(smt * 16 + l15) * 256 + (kl ^ sw)]);
      const half8_t hb = *(const half8_t*)(&Hs[sgi][(snt * 16 + l15) * 256 + (kl ^ sw)]);
      sacc = MF16(ua, hb, sacc);
    }
    #pragma unroll
    for (int jj = 0; jj < 4; ++jj)
      Sb[sgi][(smt * 16 + 4 * (g4 & 3) + jj) * 33 + snt * 16 + l15] = sacc[jj];
  }

  // ---- v[m] = h[m].Wv + bv ----
  {
    const int gi = tid >> 8, m = (tid >> 3) & 31, q = tid & 7;
    float s = 0.f;
    const int c0 = q * 32;
    for (int cc = 0; cc < 32; ++cc) {
      const int c = c0 + cc;
      s = fmaf((float)Hs[gi][m * 256 + (c ^ ((m & 15) << 3))], Wvp[c], s);
    }
    s += __shfl_xor(s, 1);
    s += __shfl_xor(s, 2);
    s += __shfl_xor(s, 4);
    if (q == 0) Sb[gi][1120 + m] = s + bv[0];
  }
  __syncthreads();

  // ---- row softmax fused with w = attn @ v ----
  if (tid < 64) {
    const int gi = tid >> 5, n = tid & 31;
    float mx = -1e30f;
    #pragma unroll 1
    for (int m = 0; m < NN; ++m) mx = fmaxf(mx, Sb[gi][n * 33 + m]);
    float se = 0.f, sv = 0.f;
    #pragma unroll 1
    for (int m = 0; m < NN; ++m) {
      const float e = expf(Sb[gi][n * 33 + m] - mx);
      se += e;
      sv = fmaf(e, Sb[gi][1120 + m], sv);
    }
    Sb[gi][1152 + n] = sv / se;
  }
  __syncthreads();

  // ---- feats = h^T @ w  -> Fh fp16 [4096][288] ----
  {
    const int gi = tid >> 8, j = tid & 255;
    float f0 = 0.f;
    #pragma unroll
    for (int m = 0; m < NN; ++m) {
      const float w = Sb[gi][1152 + m];
      f0 = fmaf((float)Hs[gi][m * 256 + (j ^ ((m & 15) << 3))], w, f0);
    }
    Fh[(size_t)(ga + gi) * FSTR + j] = (_Float16)f0;
    if (tid < 64) {
      const int g2b = tid >> 5, c = 256 + (tid & 31);
      Fh[(size_t)(ga + g2b) * FSTR + c] =
          (c < FDIM) ? (_Float16)addf[(size_t)(ga + g2b) * ADDD + (c - 256)] : (_Float16)0.f;
    }
  }
}

// ---------------------------------------------------------------------------
// Kernel 2: MFMA MLP (unchanged — ~6 µs).
// ---------------------------------------------------------------------------
__global__ __launch_bounds__(512, 4)
void mlp_kernel(const _Float16* __restrict__ Fh,
                const _Float16* __restrict__ W1p, const float* __restrict__ b1,
                const _Float16* __restrict__ W2p, const float* __restrict__ b2,
                const float* __restrict__ W3, const float* __restrict__ b3,
                float* __restrict__ out)
{
  __shared__ __align__(16) _Float16 Ft[16 * 320];
  __shared__ __align__(16) _Float16 Z1[16 * 1024];
  __shared__ __align__(16) _Float16 Z2[16 * 512];

  const int tid = threadIdx.x, lane = tid & 63, wv = tid >> 6;
  const int g4 = lane >> 4, l15 = lane & 15;
  const int sw = (l15 & 7) << 3;
  const int r0 = blockIdx.x * 16;

  for (int i = tid; i < 16 * FSTR; i += 512) {
    const int r = i / FSTR, c = i - r * FSTR;
    Ft[r * 320 + (c ^ ((r & 7) << 3))] = Fh[(size_t)(r0 + r) * FSTR + c];
  }
  __syncthreads();

  // layer 1: z1^T = W1^T @ Ft^T
  {
    float4_t a1[8];
    #pragma unroll
    for (int t = 0; t < 8; ++t) a1[t] = (float4_t){0.f, 0.f, 0.f, 0.f};
    #pragma unroll
    for (int ks = 0; ks < 9; ++ks) {
      const half8_t fb = *(const half8_t*)(Ft + l15 * 320 + ((ks * 32 + g4 * 8) ^ sw));
      #pragma unroll
      for (int t = 0; t < 8; ++t) {
        const int jt = wv * 8 + t;
        const half8_t wf = *(const half8_t*)(W1p + ((size_t)(jt * 9 + ks) * 64 + lane) * 8);
        a1[t] = MF16(wf, fb, a1[t]);
      }
    }
    #pragma unroll
    for (int t = 0; t < 8; ++t) {
      const int j0 = (wv * 8 + t) * 16 + 4 * g4;
      const float4 bb = *(const float4*)&b1[j0];
      H4 pk4;
      #pragma unroll
      for (int jj = 0; jj < 4; ++jj) {
        const float z = a1[t][jj] + ((const float*)&bb)[jj];
        pk4.h[jj] = (_Float16)fmaxf(z, 0.01f * z);
      }
      *(unsigned long long*)(Z1 + l15 * 1024 + (j0 ^ sw)) = pk4.u;
    }
  }
  __syncthreads();

  // layer 2: z2^T = W2^T @ z1^T
  {
    float4_t a2[4];
    #pragma unroll
    for (int t = 0; t < 4; ++t) a2[t] = (float4_t){0.f, 0.f, 0.f, 0.f};
    #pragma unroll 4
    for (int ks = 0; ks < 32; ++ks) {
      const half8_t zb = *(const half8_t*)(Z1 + l15 * 1024 + ((ks * 32 + g4 * 8) ^ sw));
      #pragma unroll
      for (int t = 0; t < 4; ++t) {
        const int jt = wv * 4 + t;
        const half8_t wf = *(const half8_t*)(W2p + ((size_t)(jt * 32 + ks) * 64 + lane) * 8);
        a2[t] = MF16(wf, zb, a2[t]);
      }
    }
    #pragma unroll
    for (int t = 0; t < 4; ++t) {
      const int j0 = (wv * 4 + t) * 16 + 4 * g4;
      const float4 bb = *(const float4*)&b2[j0];
      H4 pk4;
      #pragma unroll
      for (int jj = 0; jj < 4; ++jj) {
        const float z = a2[t][jj] + ((const float*)&bb)[jj];
        pk4.h[jj] = (_Float16)fmaxf(z, 0.01f * z);
      }
      *(unsigned long long*)(Z2 + l15 * 512 + (j0 ^ sw)) = pk4.u;
    }
  }
  __syncthreads();

  // layer 3: out = z2 @ W3 + b3
  {
    const int m = tid >> 5, q = tid & 31;
    const int swm = (m & 7) << 3;
    float s = 0.f;
    #pragma unroll
    for (int h = 0; h < 2; ++h) {
      const int c0 = q * 16 + h * 8;
      const half8_t z8 = *(const half8_t*)(Z2 + m * 512 + (c0 ^ swm));
      #pragma unroll
      for (int i2 = 0; i2 < 8; ++i2)
        s = fmaf((float)z8[i2], W3[c0 + i2], s);
    }
    s += __shfl_xor(s, 1);
    s += __shfl_xor(s, 2);
    s += __shfl_xor(s, 4);
    s += __shfl_xor(s, 8);
    s += __shfl_xor(s, 16);
    if (q == 0) out[r0 + m] = s + b3[0];
  }
}

// ---------------------------------------------------------------------------
extern "C" void kernel_launch(void* const* d_in, const int* in_sizes, int n_in,
                              void* d_out, int out_size, void* d_ws, size_t ws_size,
                              hipStream_t stream) {
  (void)in_sizes; (void)n_in; (void)out_size; (void)ws_size;
  const float* x    = (const float*)d_in[0];
  const float* addf = (const float*)d_in[1];
  const int*   src  = (const int*)d_in[2];
  const int*   dst  = (const int*)d_in[3];
  const float* W_in = (const float*)d_in[4];
  const float* b_in = (const float*)d_in[5];
  const float* W_g1 = (const float*)d_in[6];
  const float* b_g1 = (const float*)d_in[7];
  const float* W_g2 = (const float*)d_in[8];
  const float* b_g2 = (const float*)d_in[9];
  const float* Wq   = (const float*)d_in[10];
  const float* bq   = (const float*)d_in[11];
  const float* Wk   = (const float*)d_in[12];
  // d_in[13] = bk : cancels in softmax (row-constant), unused
  const float* Wv   = (const float*)d_in[14];
  const float* bv   = (const float*)d_in[15];
  const float* W1   = (const float*)d_in[16];
  const float* b1   = (const float*)d_in[17];
  const float* W2   = (const float*)d_in[18];
  const float* b2   = (const float*)d_in[19];
  const float* W3   = (const float*)d_in[20];
  const float* b3   = (const float*)d_in[21];
  float* out = (float*)d_out;

  _Float16* Fh    = (_Float16*)((char*)d_ws + WS_FH);
  float* wqkf     = (float*)((char*)d_ws + WS_WQK);
  float* tvec     = (float*)((char*)d_ws + WS_TVEC);
  _Float16* pk    = (_Float16*)((char*)d_ws + WS_PK);

  prep1_kernel<<<dim3(257), dim3(256), 0, stream>>>(Wq, Wk, bq, wqkf, tvec);
  prep2_kernel<<<dim3(364), dim3(256), 0, stream>>>(W_in, W_g1, W_g2, wqkf, pk);
  prep3_kernel<<<dim3(400), dim3(256), 0, stream>>>(W1, W2, pk);
  gnn_kernel<<<dim3(BB / 2), dim3(512), 0, stream>>>(
      x, addf, src, dst, b_in, b_g1, b_g2, Wv, bv, pk, tvec, Fh);
  mlp_kernel<<<dim3(BB / 16), dim3(512), 0, stream>>>(
      Fh, pk + PK_W1P, b1, pk + PK_W2P, b2, W3, b3, out);
}

// Round 18
// 280.070 us; speedup vs baseline: 1.3773x; 1.3773x over previous
//
#include <hip/hip_runtime.h>
#include <math.h>

#define BB     4096
#define NN     32
#define EE     64
#define INDIM  74
#define HH     256
#define GCR    5
#define M1     1024
#define M2     512
#define FDIM   258
#define ADDD   2
#define FSTR   288     // Fh row stride (fp16), cols 258..287 zero

typedef __attribute__((ext_vector_type(8))) _Float16 half8_t;
typedef __attribute__((ext_vector_type(4))) float float4_t;

#define MF16(a, b, c) __builtin_amdgcn_mfma_f32_16x16x32_f16((a), (b), (c), 0, 0, 0)
#define LO_SCALE 1024.0f

// ---- ws layout (bytes) ----
#define WS_FH     0               // Fh fp16 [4096][288]
#define WS_WQK    4227072         // Wqk fp32 [256][256]
#define WS_TVEC   4489216         // tvec fp32 [256]
#define WS_PK     4490240         // packed fp16 fragments
// offsets in _Float16 units from PK base:
#define PK_WIN_HI 0
#define PK_WIN_LO 24576
#define PK_G_BASE 49152
#define PK_G_STRIDE 131072
#define PK_WQK_HI 1359872
#define PK_WQK_LO (1359872 + 65536)
#define PK_W1P    1490944
#define PK_W2P    1785856

union H4 { unsigned long long u; _Float16 h[4]; };

// ---------------------------------------------------------------------------
// Prep 1: Wqk = Wq @ Wk^T (fp32), tvec = Wk @ bq
// ---------------------------------------------------------------------------
__global__ void prep1_kernel(const float* __restrict__ Wq, const float* __restrict__ Wk,
                             const float* __restrict__ bq,
                             float* __restrict__ wqkf, float* __restrict__ tvec) {
  const int i = blockIdx.x, j = threadIdx.x;
  if (i < 256) {
    __shared__ float qrow[256];
    qrow[j] = Wq[i * 256 + j];
    __syncthreads();
    float s = 0.f;
    for (int c = 0; c < 256; ++c) s = fmaf(qrow[c], Wk[j * 256 + c], s);
    wqkf[i * 256 + j] = s;
  } else {
    float s = 0.f;
    for (int c = 0; c < 256; ++c) s = fmaf(Wk[j * 256 + c], bq[c], s);
    tvec[j] = s;
  }
}

// ---------------------------------------------------------------------------
// Prep 2: pack GNN weights into MFMA B-frag order (fp16 hi; lo legacy-unused).
// ---------------------------------------------------------------------------
template<int KS, int KREAL>
__device__ __forceinline__ void pack_one(const float* __restrict__ S,
                                         _Float16* __restrict__ hi,
                                         _Float16* __restrict__ lo, int local) {
  const int l = local & 63;
  const int nk = local >> 6;
  const int ks = nk % KS;
  const int nt = nk / KS;
  const int j = nt * 16 + (l & 15);
  const int kbase = ks * 32 + (l >> 4) * 8;
  half8_t h8, l8;
  #pragma unroll
  for (int i = 0; i < 8; ++i) {
    const int k = kbase + i;
    const float v = (k < KREAL) ? S[k * 256 + j] : 0.f;
    const _Float16 hb = (_Float16)v;
    h8[i] = hb;
    l8[i] = (_Float16)((v - (float)hb) * LO_SCALE);
  }
  *(half8_t*)(hi + (size_t)local * 8) = h8;
  *(half8_t*)(lo + (size_t)local * 8) = l8;
}

__global__ void prep2_kernel(const float* __restrict__ W_in,
                             const float* __restrict__ W_g1, const float* __restrict__ W_g2,
                             const float* __restrict__ wqkf, _Float16* __restrict__ pk) {
  const int cid = blockIdx.x * 256 + threadIdx.x;
  if (cid < 3072) {
    pack_one<3, 74>(W_in, pk + PK_WIN_HI, pk + PK_WIN_LO, cid);
  } else {
    const int m = (cid - 3072) >> 13;               // 0..10
    const int local = (cid - 3072) & 8191;
    _Float16* hi; const float* S;
    if (m < 10) {
      hi = pk + PK_G_BASE + (size_t)m * PK_G_STRIDE;
      S = (m < 5) ? (W_g1 + (size_t)m * 65536) : (W_g2 + (size_t)(m - 5) * 65536);
    } else {
      hi = pk + PK_WQK_HI;
      S = wqkf;
    }
    pack_one<8, 256>(S, hi, hi + 65536, local);
  }
}

// ---------------------------------------------------------------------------
// Prep 3: pack MLP weights (W1 [258][1024], W2 [1024][512]) fp16 A'-frag order.
// ---------------------------------------------------------------------------
template<int KS, int KREAL, int NCOL>
__device__ __forceinline__ void pack_flat(const float* __restrict__ S,
                                          _Float16* __restrict__ dst, int local) {
  const int l = local & 63;
  const int nk = local >> 6;
  const int ks = nk % KS;
  const int nt = nk / KS;
  const int j = nt * 16 + (l & 15);
  const int kbase = ks * 32 + (l >> 4) * 8;
  half8_t h8;
  #pragma unroll
  for (int i = 0; i < 8; ++i) {
    const int k = kbase + i;
    h8[i] = (_Float16)((k < KREAL) ? S[(size_t)k * NCOL + j] : 0.f);
  }
  *(half8_t*)(dst + (size_t)local * 8) = h8;
}

__global__ void prep3_kernel(const float* __restrict__ W1, const float* __restrict__ W2,
                             _Float16* __restrict__ pk) {
  const int cid = blockIdx.x * 256 + threadIdx.x;
  if (cid < 36864) {
    pack_flat<9, 258, 1024>(W1, pk + PK_W1P, cid);
  } else {
    pack_flat<32, 1024, 512>(W2, pk + PK_W2P, cid - 36864);
  }
}

// ---------------------------------------------------------------------------
// conv for 2 graphs, 8 waves, zero cross-barrier register state:
//   MFMA1 both phases -> T tiles (both) into Tb (wave-private)
//   barrier (all H reads done)
//   MFMA2 both phases (T from LDS, Nmat single-fp16 from NmF) -> H direct
//   barrier
// Hs layout: n*256 + (j ^ ((n&15)<<3)) — 4 row bits spread the 16 l15-lanes
// over all 16 even start-banks (r12's 3-bit form was half-bank, 2x loss).
// Tb: gi*8192 + nt*512 + frag (linear).
// ---------------------------------------------------------------------------
template<int KS, bool RELU>
__device__ __forceinline__ void conv2x(
    _Float16* Hs, _Float16* Tb, const _Float16* NmF,
    const _Float16* __restrict__ Whi,
    const float* __restrict__ bias,
    int lane, int wv)
{
  const int g4 = lane >> 4, l15 = lane & 15;
  const int sw = l15 << 3;            // row&15 == l15 for rows mt*16+l15

  #pragma unroll
  for (int p = 0; p < 2; ++p) {
    const int nt = p * 8 + wv;
    float4_t th[2][2];
    #pragma unroll
    for (int a = 0; a < 2; ++a)
      #pragma unroll
      for (int b = 0; b < 2; ++b)
        th[a][b] = (float4_t){0.f, 0.f, 0.f, 0.f};
    #pragma unroll
    for (int ks = 0; ks < KS; ++ks) {
      const int off = ((nt * KS + ks) * 64 + lane) * 8;
      const half8_t wh = *(const half8_t*)(Whi + off);
      const int j0 = ks * 32 + g4 * 8;
      #pragma unroll
      for (int gi = 0; gi < 2; ++gi)
        #pragma unroll
        for (int mt = 0; mt < 2; ++mt) {
          const half8_t ha = *(const half8_t*)(Hs + (gi << 13) + ((mt * 16 + l15) * 256 + (j0 ^ sw)));
          th[gi][mt] = MF16(ha, wh, th[gi][mt]);
        }
    }
    #pragma unroll
    for (int gi = 0; gi < 2; ++gi)
      #pragma unroll
      for (int mt = 0; mt < 2; ++mt) {
        const int r0 = mt * 16 + 4 * g4;
        H4 pk4;
        #pragma unroll
        for (int jj = 0; jj < 4; ++jj)
          pk4.h[jj] = (_Float16)th[gi][mt][jj];
        const int idx = nt * 512 + ((r0 >> 3) * 16 + l15) * 8 + (r0 & 7);
        *(unsigned long long*)(Tb + (gi << 13) + idx) = pk4.u;
      }
  }

  __syncthreads();   // ALL waves' H reads (both phases) complete

  #pragma unroll
  for (int p = 0; p < 2; ++p) {
    const int nt = p * 8 + wv;
    const float4 b4 = *(const float4*)&bias[nt * 16 + 4 * g4];
    const int j0 = nt * 16 + 4 * g4;
    #pragma unroll
    for (int gi = 0; gi < 2; ++gi) {
      const half8_t ta = *(const half8_t*)(Tb + (gi << 13) + nt * 512 + lane * 8);
      #pragma unroll
      for (int nt2 = 0; nt2 < 2; ++nt2) {
        const half8_t nmh = *(const half8_t*)(NmF + ((gi * 2 + nt2) * 64 + lane) * 8);
        const float4_t dh = MF16(ta, nmh, ((float4_t){0.f, 0.f, 0.f, 0.f}));
        H4 pk4;
        #pragma unroll
        for (int jj = 0; jj < 4; ++jj) {
          float v = dh[jj] + ((const float*)&b4)[jj];
          if (RELU) v = fmaxf(v, 0.f);
          pk4.h[jj] = (_Float16)v;
        }
        const int n = nt2 * 16 + l15;
        *(unsigned long long*)(Hs + (gi << 13) + (n * 256 + (j0 ^ ((n & 15) << 3)))) = pk4.u;
      }
    }
  }
  __syncthreads();   // new h visible
}

// ---------------------------------------------------------------------------
// GNN kernel: 2 graphs/block, 512 threads. LDS: Hs 32K + Tb 32K + NmF 4K +
// Sb 9.25K = 77.5 KB -> 2 blocks/CU under (512,4). Best-validated config
// (r13, 279.9 us): spill-free, conflicts 1.67e7, MfmaUtil ~36%.
// ---------------------------------------------------------------------------
__global__ __launch_bounds__(512, 4)
void gnn_kernel(const float* __restrict__ x, const float* __restrict__ addf,
                const int* __restrict__ src, const int* __restrict__ dst,
                const float* __restrict__ b_in,
                const float* __restrict__ b_g1, const float* __restrict__ b_g2,
                const float* __restrict__ Wvp, const float* __restrict__ bv,
                const _Float16* __restrict__ pk,
                const float* __restrict__ tvec,
                _Float16* __restrict__ Fh)
{
  __shared__ __align__(16) _Float16 Hs[2][8192];
  __shared__ __align__(16) _Float16 Tb[2][8192];
  __shared__ __align__(16) _Float16 NmF[2048];
  __shared__ float Sb[2][1184];

  const int tid = threadIdx.x;
  const int lane = tid & 63;
  const int wv = tid >> 6;            // 0..7
  const int g4 = lane >> 4, l15 = lane & 15;
  const int sw = l15 << 3;
  const int ga = blockIdx.x * 2;

  // ---- build Nmat = diag(inorm) . A_adj . diag(onorm) for both graphs ----
  for (int i = tid; i < 2048; i += 512) Sb[i >> 10][i & 1023] = 0.f;
  __syncthreads();
  if (tid < 128) {
    const int gi = tid >> 6, e = tid & 63;
    const int es = src[(size_t)(ga + gi) * EE + e];
    const int ed = dst[(size_t)(ga + gi) * EE + e];
    atomicAdd(&Sb[gi][ed * 32 + es], 1.0f);
  }
  __syncthreads();
  if (tid < 64) {                       // inorm = rsqrt(row sums)
    const int gi = tid >> 5, n = tid & 31;
    float s = 0.f;
    for (int m = 0; m < NN; ++m) s += Sb[gi][n * 32 + m];
    Sb[gi][1056 + n] = 1.f / sqrtf(fmaxf(s, 1.f));
  } else if (tid < 128) {               // onorm = rsqrt(col sums)
    const int gi = (tid - 64) >> 5, n = tid & 31;
    float s = 0.f;
    for (int m = 0; m < NN; ++m) s += Sb[gi][m * 32 + n];
    Sb[gi][1088 + n] = 1.f / sqrtf(fmaxf(s, 1.f));
  }
  __syncthreads();
  for (int i = tid; i < 2048; i += 512) {
    const int gi = i >> 10, idx = i & 1023;
    Sb[gi][idx] *= Sb[gi][1056 + (idx >> 5)] * Sb[gi][1088 + (idx & 31)];
  }
  __syncthreads();

  // ---- Nmat B-fragments (single fp16) into NmF (wave 0 builds) ----
  if (wv == 0) {
    #pragma unroll
    for (int gi = 0; gi < 2; ++gi) {
      #pragma unroll
      for (int nt2 = 0; nt2 < 2; ++nt2) {
        half8_t h8;
        #pragma unroll
        for (int i = 0; i < 8; ++i)
          h8[i] = (_Float16)Sb[gi][(nt2 * 16 + l15) * 32 + g4 * 8 + i];
        *(half8_t*)(NmF + ((gi * 2 + nt2) * 64 + lane) * 8) = h8;
      }
    }
  }

  // ---- stage x (fp16, cols 74..95 zero) ----
  for (int i = tid; i < 2 * NN * 96; i += 512) {
    const int gi = i / 3072, rem = i - gi * 3072;
    const int r = rem / 96, c = rem - r * 96;
    const float vx = (c < INDIM) ? x[(size_t)(ga + gi) * (NN * INDIM) + r * INDIM + c] : 0.f;
    Hs[gi][r * 256 + (c ^ ((r & 15) << 3))] = (_Float16)vx;
  }
  __syncthreads();

  // ---- 11 graph convolutions ----
  conv2x<3, false>(&Hs[0][0], &Tb[0][0], NmF, pk + PK_WIN_HI, b_in, lane, wv);
  #pragma unroll 1
  for (int L = 0; L < GCR; ++L) {
    conv2x<8, true>(&Hs[0][0], &Tb[0][0], NmF,
                    pk + PK_G_BASE + (size_t)L * PK_G_STRIDE, b_g1 + L * HH, lane, wv);
    conv2x<8, true>(&Hs[0][0], &Tb[0][0], NmF,
                    pk + PK_G_BASE + (size_t)(5 + L) * PK_G_STRIDE, b_g2 + L * HH, lane, wv);
  }

  // ---- attention ----
  {
    const _Float16* Qhi = pk + PK_WQK_HI;
    const int sgi = wv >> 2, smt = (wv >> 1) & 1, snt = wv & 1;
    float4_t sacc = (float4_t){0.f, 0.f, 0.f, 0.f};

    #pragma unroll
    for (int p = 0; p < 2; ++p) {
      const int nt = p * 8 + wv;
      float4_t uh[2][2];
      #pragma unroll
      for (int a = 0; a < 2; ++a)
        #pragma unroll
        for (int b = 0; b < 2; ++b)
          uh[a][b] = (float4_t){0.f, 0.f, 0.f, 0.f};
      #pragma unroll
      for (int ks = 0; ks < 8; ++ks) {
        const int off = ((nt * 8 + ks) * 64 + lane) * 8;
        const half8_t qh = *(const half8_t*)(Qhi + off);
        const int j0 = ks * 32 + g4 * 8;
        #pragma unroll
        for (int gi = 0; gi < 2; ++gi)
          #pragma unroll
          for (int mt = 0; mt < 2; ++mt) {
            const half8_t ha = *(const half8_t*)(&Hs[gi][(mt * 16 + l15) * 256 + (j0 ^ sw)]);
            uh[gi][mt] = MF16(ha, qh, uh[gi][mt]);
          }
      }
      const float tv = tvec[nt * 16 + l15];
      const int cl = wv * 16 + l15;
      #pragma unroll
      for (int gi = 0; gi < 2; ++gi)
        #pragma unroll
        for (int mt = 0; mt < 2; ++mt)
          #pragma unroll
          for (int jj = 0; jj < 4; ++jj) {
            const int n = mt * 16 + 4 * g4 + jj;
            Tb[gi][n * 128 + (cl ^ ((n & 15) << 3))] =
                (_Float16)(uh[gi][mt][jj] + tv);
          }
      __syncthreads();
      #pragma unroll
      for (int ksl = 0; ksl < 4; ++ksl) {
        const int kl = ksl * 32 + g4 * 8;
        const half8_t ua = *(const half8_t*)(&Tb[sgi][(smt * 16 + l15) * 128 + (kl ^ sw)]);
        const half8_t hb = *(const half8_t*)(&Hs[sgi][(snt * 16 + l15) * 256 + ((p * 128 + kl) ^ sw)]);
        sacc = MF16(ua, hb, sacc);
      }
      __syncthreads();
    }
    #pragma unroll
    for (int jj = 0; jj < 4; ++jj)
      Sb[sgi][(smt * 16 + 4 * g4 + jj) * 33 + snt * 16 + l15] = sacc[jj];
  }

  // ---- v[m] = h[m].Wv + bv ----
  {
    const int gi = tid >> 8, m = (tid >> 3) & 31, q = tid & 7;
    float s = 0.f;
    const int c0 = q * 32;
    for (int cc = 0; cc < 32; ++cc) {
      const int c = c0 + cc;
      s = fmaf((float)Hs[gi][m * 256 + (c ^ ((m & 15) << 3))], Wvp[c], s);
    }
    s += __shfl_xor(s, 1);
    s += __shfl_xor(s, 2);
    s += __shfl_xor(s, 4);
    if (q == 0) Sb[gi][1120 + m] = s + bv[0];
  }
  __syncthreads();

  // ---- row softmax fused with w = attn @ v ----
  if (tid < 64) {
    const int gi = tid >> 5, n = tid & 31;
    float mx = -1e30f;
    #pragma unroll 1
    for (int m = 0; m < NN; ++m) mx = fmaxf(mx, Sb[gi][n * 33 + m]);
    float se = 0.f, sv = 0.f;
    #pragma unroll 1
    for (int m = 0; m < NN; ++m) {
      const float e = expf(Sb[gi][n * 33 + m] - mx);
      se += e;
      sv = fmaf(e, Sb[gi][1120 + m], sv);
    }
    Sb[gi][1152 + n] = sv / se;
  }
  __syncthreads();

  // ---- feats = h^T @ w  -> Fh fp16 [4096][288] ----
  {
    const int gi = tid >> 8, j = tid & 255;
    float f0 = 0.f;
    #pragma unroll
    for (int m = 0; m < NN; ++m) {
      const float w = Sb[gi][1152 + m];
      f0 = fmaf((float)Hs[gi][m * 256 + (j ^ ((m & 15) << 3))], w, f0);
    }
    Fh[(size_t)(ga + gi) * FSTR + j] = (_Float16)f0;
    if (tid < 64) {
      const int g2 = tid >> 5, c = 256 + (tid & 31);
      Fh[(size_t)(ga + g2) * FSTR + c] =
          (c < FDIM) ? (_Float16)addf[(size_t)(ga + g2) * ADDD + (c - 256)] : (_Float16)0.f;
    }
  }
}

// ---------------------------------------------------------------------------
// Kernel 2: MFMA MLP (~6 µs).
// ---------------------------------------------------------------------------
__global__ __launch_bounds__(512, 4)
void mlp_kernel(const _Float16* __restrict__ Fh,
                const _Float16* __restrict__ W1p, const float* __restrict__ b1,
                const _Float16* __restrict__ W2p, const float* __restrict__ b2,
                const float* __restrict__ W3, const float* __restrict__ b3,
                float* __restrict__ out)
{
  __shared__ __align__(16) _Float16 Ft[16 * 320];
  __shared__ __align__(16) _Float16 Z1[16 * 1024];
  __shared__ __align__(16) _Float16 Z2[16 * 512];

  const int tid = threadIdx.x, lane = tid & 63, wv = tid >> 6;
  const int g4 = lane >> 4, l15 = lane & 15;
  const int sw = (l15 & 7) << 3;
  const int r0 = blockIdx.x * 16;

  for (int i = tid; i < 16 * FSTR; i += 512) {
    const int r = i / FSTR, c = i - r * FSTR;
    Ft[r * 320 + (c ^ ((r & 7) << 3))] = Fh[(size_t)(r0 + r) * FSTR + c];
  }
  __syncthreads();

  // layer 1: z1^T = W1^T @ Ft^T
  {
    float4_t a1[8];
    #pragma unroll
    for (int t = 0; t < 8; ++t) a1[t] = (float4_t){0.f, 0.f, 0.f, 0.f};
    #pragma unroll
    for (int ks = 0; ks < 9; ++ks) {
      const half8_t fb = *(const half8_t*)(Ft + l15 * 320 + ((ks * 32 + g4 * 8) ^ sw));
      #pragma unroll
      for (int t = 0; t < 8; ++t) {
        const int jt = wv * 8 + t;
        const half8_t wf = *(const half8_t*)(W1p + ((size_t)(jt * 9 + ks) * 64 + lane) * 8);
        a1[t] = MF16(wf, fb, a1[t]);
      }
    }
    #pragma unroll
    for (int t = 0; t < 8; ++t) {
      const int j0 = (wv * 8 + t) * 16 + 4 * g4;
      const float4 bb = *(const float4*)&b1[j0];
      H4 pk4;
      #pragma unroll
      for (int jj = 0; jj < 4; ++jj) {
        const float z = a1[t][jj] + ((const float*)&bb)[jj];
        pk4.h[jj] = (_Float16)fmaxf(z, 0.01f * z);
      }
      *(unsigned long long*)(Z1 + l15 * 1024 + (j0 ^ sw)) = pk4.u;
    }
  }
  __syncthreads();

  // layer 2: z2^T = W2^T @ z1^T
  {
    float4_t a2[4];
    #pragma unroll
    for (int t = 0; t < 4; ++t) a2[t] = (float4_t){0.f, 0.f, 0.f, 0.f};
    #pragma unroll 4
    for (int ks = 0; ks < 32; ++ks) {
      const half8_t zb = *(const half8_t*)(Z1 + l15 * 1024 + ((ks * 32 + g4 * 8) ^ sw));
      #pragma unroll
      for (int t = 0; t < 4; ++t) {
        const int jt = wv * 4 + t;
        const half8_t wf = *(const half8_t*)(W2p + ((size_t)(jt * 32 + ks) * 64 + lane) * 8);
        a2[t] = MF16(wf, zb, a2[t]);
      }
    }
    #pragma unroll
    for (int t = 0; t < 4; ++t) {
      const int j0 = (wv * 4 + t) * 16 + 4 * g4;
      const float4 bb = *(const float4*)&b2[j0];
      H4 pk4;
      #pragma unroll
      for (int jj = 0; jj < 4; ++jj) {
        const float z = a2[t][jj] + ((const float*)&bb)[jj];
        pk4.h[jj] = (_Float16)fmaxf(z, 0.01f * z);
      }
      *(unsigned long long*)(Z2 + l15 * 512 + (j0 ^ sw)) = pk4.u;
    }
  }
  __syncthreads();

  // layer 3: out = z2 @ W3 + b3
  {
    const int m = tid >> 5, q = tid & 31;
    const int swm = (m & 7) << 3;
    float s = 0.f;
    #pragma unroll
    for (int h = 0; h < 2; ++h) {
      const int c0 = q * 16 + h * 8;
      const half8_t z8 = *(const half8_t*)(Z2 + m * 512 + (c0 ^ swm));
      #pragma unroll
      for (int i2 = 0; i2 < 8; ++i2)
        s = fmaf((float)z8[i2], W3[c0 + i2], s);
    }
    s += __shfl_xor(s, 1);
    s += __shfl_xor(s, 2);
    s += __shfl_xor(s, 4);
    s += __shfl_xor(s, 8);
    s += __shfl_xor(s, 16);
    if (q == 0) out[r0 + m] = s + b3[0];
  }
}

// ---------------------------------------------------------------------------
extern "C" void kernel_launch(void* const* d_in, const int* in_sizes, int n_in,
                              void* d_out, int out_size, void* d_ws, size_t ws_size,
                              hipStream_t stream) {
  (void)in_sizes; (void)n_in; (void)out_size; (void)ws_size;
  const float* x    = (const float*)d_in[0];
  const float* addf = (const float*)d_in[1];
  const int*   src  = (const int*)d_in[2];
  const int*   dst  = (const int*)d_in[3];
  const float* W_in = (const float*)d_in[4];
  const float* b_in = (const float*)d_in[5];
  const float* W_g1 = (const float*)d_in[6];
  const float* b_g1 = (const float*)d_in[7];
  const float* W_g2 = (const float*)d_in[8];
  const float* b_g2 = (const float*)d_in[9];
  const float* Wq   = (const float*)d_in[10];
  const float* bq   = (const float*)d_in[11];
  const float* Wk   = (const float*)d_in[12];
  // d_in[13] = bk : cancels in softmax (row-constant), unused
  const float* Wv   = (const float*)d_in[14];
  const float* bv   = (const float*)d_in[15];
  const float* W1   = (const float*)d_in[16];
  const float* b1   = (const float*)d_in[17];
  const float* W2   = (const float*)d_in[18];
  const float* b2   = (const float*)d_in[19];
  const float* W3   = (const float*)d_in[20];
  const float* b3   = (const float*)d_in[21];
  float* out = (float*)d_out;

  _Float16* Fh    = (_Float16*)((char*)d_ws + WS_FH);
  float* wqkf     = (float*)((char*)d_ws + WS_WQK);
  float* tvec     = (float*)((char*)d_ws + WS_TVEC);
  _Float16* pk    = (_Float16*)((char*)d_ws + WS_PK);

  prep1_kernel<<<dim3(257), dim3(256), 0, stream>>>(Wq, Wk, bq, wqkf, tvec);
  prep2_kernel<<<dim3(364), dim3(256), 0, stream>>>(W_in, W_g1, W_g2, wqkf, pk);
  prep3_kernel<<<dim3(400), dim3(256), 0, stream>>>(W1, W2, pk);
  gnn_kernel<<<dim3(BB / 2), dim3(512), 0, stream>>>(
      x, addf, src, dst, b_in, b_g1, b_g2, Wv, bv, pk, tvec, Fh);
  mlp_kernel<<<dim3(BB / 16), dim3(512), 0, stream>>>(
      Fh, pk + PK_W1P, b1, pk + PK_W2P, b2, W3, b3, out);
}